// Round 9
// baseline (255.832 us; speedup 1.0000x reference)
//
#include <hip/hip_runtime.h>
#include <hip/hip_fp16.h>

// CommNet critic forward, fully fused: 1 workgroup = 2 batches (64 agent-rows).
// All GEMMs via v_mfma_f32_16x16x32_f16 (fp32 accumulate). B=2048,A=32,D=128,H=256.
// V10: algebraic GRU2 restructure. c = (S - h1)/32 (S = per-batch colsum of h1), so
//      gi = gS/32 - (h1 @ W_ih^T)/32. Prep stores COMB = W_hh - W_ih/32 (r,z gates)
//      and WIHN = -W_ih(n)/32, letting GRU2 run entirely on A = h1:
//      per K-step {2 ds_reads, 4 B-loads, 8 MFMAs} vs V9's {4, 6, 12}.
//      comm phase removed; tiny MFMA-based ep phase computes gS/32 + biases
//      (virtual 16-row A with rows 0,1 = f16 colsums; 3 tiles x 8 ks per wave).
//      Empirical law from V2-V9: exactly 1 workgroup resident/CU -> 1024 threads,
//      and 1024-thr blocks always get a 64-VGPR budget -> keep live sets small.

#define NB   2048
#define NA   32
#define DIN  128
#define HID  256
#define SA   264   // f16 row stride for activation LDS tiles (528B stride -> 4-bank stagger)
#define MROWS 64   // 2 batches x 32 agents

typedef _Float16 half8  __attribute__((ext_vector_type(8)));
typedef float    float4v __attribute__((ext_vector_type(4)));

// f16 weight-fragment arena layout in d_ws (element offsets)
#define ENC_OFF    0        // encW,       NT=16, K=128 -> 32768
#define FOBS_OFF   32768    // fobsW,      NT=16, K=256 -> 65536
#define WIHN_OFF   98304    // -wih(n)/32, NT=16, K=256 -> 65536 (wih rows 512..767)
#define WHH_OFF    163840   // whh,        NT=48, K=256 -> 196608
#define COMB_OFF   360448   // whh-wih/32, NT=32, K=256 -> 131072 (rows 0..511: r,z)
#define PREP_TOTAL 491520   // f16 elements -> 983040 bytes needed in ws

// Pre-arrange weights into exact MFMA B-fragment order, f16:
// frag[((ks*NT + nt)*64 + lane)*8 + j] = W[row(nt,lane)][ks*32 + (lane/16)*8 + j]
__global__ void prep_weights(const float* __restrict__ encW, const float* __restrict__ fobsW,
                             const float* __restrict__ wih,  const float* __restrict__ whh,
                             _Float16* __restrict__ prep) {
    int F = blockIdx.x * 256 + threadIdx.x;
    if (F >= PREP_TOTAL) return;
    const float* srcA; const float* srcB = nullptr;
    int K, NT, local, rowoff = 0; float scA = 1.f, scB = 0.f;
    if (F < FOBS_OFF)      { srcA = encW;  K = 128; NT = 16; local = F; }
    else if (F < WIHN_OFF) { srcA = fobsW; K = 256; NT = 16; local = F - FOBS_OFF; }
    else if (F < WHH_OFF)  { srcA = wih;   K = 256; NT = 16; local = F - WIHN_OFF;
                             rowoff = 512; scA = -0.03125f; }
    else if (F < COMB_OFF) { srcA = whh;   K = 256; NT = 48; local = F - WHH_OFF; }
    else                   { srcA = whh; srcB = wih; K = 256; NT = 32;
                             local = F - COMB_OFF; scB = -0.03125f; }
    int j    = local & 7;
    int lane = (local >> 3) & 63;
    int t    = local >> 9;
    int nt   = t % NT;
    int ks   = t / NT;
    int row  = rowoff + nt * 16 + (lane & 15);
    int k    = ks * 32 + ((lane >> 4) << 3) + j;
    float v  = srcA[row * K + k] * scA;
    if (srcB) v += srcB[row * K + k] * scB;
    prep[F] = (_Float16)v;
}

// NaN-safe, clamp-free: exp saturates cleanly through the rcp.
__device__ __forceinline__ float sigmoid_f(float x) {
    return 1.f / (1.f + __expf(-x));
}
__device__ __forceinline__ float tanh_f(float x) {
    return 1.f - 2.f / (__expf(2.f * x) + 1.f);
}

// Prepped B-fragment load (16 cols x 32 k).
__device__ __forceinline__ half8 ldB(const _Float16* __restrict__ prepm, int NT, int nt, int ks,
                                     int lane) {
    return *(const half8*)(prepm + (((ks * NT + nt) * 64 + lane) << 3));
}
// Raw fp32 fallback with optional second source and scales.
__device__ __forceinline__ half8 ldBraw(const float* __restrict__ rawA, float scA,
                                        const float* __restrict__ rawB, float scB,
                                        int rowoff, int K, int nt, int ks, int lane) {
    half8 b; int l16 = lane & 15, kq = (lane >> 4) << 3;
    int row = rowoff + nt * 16 + l16;
    #pragma unroll
    for (int j = 0; j < 8; j++) {
        float v = rawA[row * K + ks * 32 + kq + j] * scA;
        if (rawB) v += rawB[row * K + ks * 32 + kq + j] * scB;
        b[j] = (_Float16)v;
    }
    return b;
}

__global__ __launch_bounds__(1024) void commnet_fused(
    const float* __restrict__ obs, const _Float16* __restrict__ prep,
    const float* __restrict__ enc_b, const float* __restrict__ fobs_b,
    const float* __restrict__ b_ih, const float* __restrict__ b_hh,
    const float* __restrict__ dec_W, const float* __restrict__ dec_b,
    float* __restrict__ out,
    const float* __restrict__ encW, const float* __restrict__ fobsW,
    const float* __restrict__ wih, const float* __restrict__ whh,
    int use_prep)
{
    const int b    = blockIdx.x;       // block handles batches 2b, 2b+1 (rows 0..63)
    const int tid  = threadIdx.x;
    const int lane = tid & 63;
    const int nt   = tid >> 6;         // wave 0..15 -> col tile nt (cols 16nt..16nt+15)
    const int l16  = lane & 15;
    const int quad = lane >> 4;
    const int kq   = quad << 3;
    const int col  = nt * 16 + l16;    // this lane's output column (fixed all phases)

    __shared__ __align__(16) _Float16 sA[2][MROWS * SA];
    __shared__ __align__(16) float Scol[2][HID];     // per-batch column sums of h1
    __shared__ __align__(16) float ep[2][3 * HID];   // per-batch gS/32 + biases (r,z,n)
    __shared__ float Srow[MROWS];                    // decoder row accumulators

    // ---- stage obs (fp32 global -> f16 LDS): 64 rows x 128, one half8 per thread
    {
        const float* obsb = obs + (size_t)b * MROWS * DIN;
        int r   = tid >> 4;            // 16 chunks per 128-wide row, 64 rows
        int off = (tid & 15) << 3;
        const float* src = obsb + r * DIN + off;
        float4v v0 = *(const float4v*)(src);
        float4v v1 = *(const float4v*)(src + 4);
        half8 hv;
        hv[0] = (_Float16)v0[0]; hv[1] = (_Float16)v0[1];
        hv[2] = (_Float16)v0[2]; hv[3] = (_Float16)v0[3];
        hv[4] = (_Float16)v1[0]; hv[5] = (_Float16)v1[1];
        hv[6] = (_Float16)v1[2]; hv[7] = (_Float16)v1[3];
        *(half8*)(&sA[0][r * SA + off]) = hv;
    }
    __syncthreads();

    // ---- encoder: e = relu(obs @ encW^T + enc_b) : T0 -> T1
    {
        float4v acc[4];
        float4v z = {0.f, 0.f, 0.f, 0.f};
        acc[0] = z; acc[1] = z; acc[2] = z; acc[3] = z;
        #pragma unroll
        for (int ks = 0; ks < 4; ks++) {
            int kbase = ks * 32 + kq;
            half8 Af[4];
            #pragma unroll
            for (int mt = 0; mt < 4; mt++)
                Af[mt] = *(const half8*)(&sA[0][(mt * 16 + l16) * SA + kbase]);
            half8 b0 = use_prep ? ldB(prep + ENC_OFF, 16, nt, ks, lane)
                                : ldBraw(encW, 1.f, nullptr, 0.f, 0, DIN, nt, ks, lane);
            #pragma unroll
            for (int mt = 0; mt < 4; mt++)
                acc[mt] = __builtin_amdgcn_mfma_f32_16x16x32_f16(Af[mt], b0, acc[mt], 0, 0, 0);
        }
        float bb = enc_b[col];
        #pragma unroll
        for (int mt = 0; mt < 4; mt++)
            #pragma unroll
            for (int r = 0; r < 4; r++) {
                int row = mt * 16 + quad * 4 + r;
                sA[1][row * SA + col] = (_Float16)fmaxf(acc[mt][r] + bb, 0.f);
            }
    }
    __syncthreads();

    // ---- fobs: h = e @ fobsW^T + fobs_b : T1 -> T0. Keep h (f32) in regs as GRU1's hold.
    float4v hacc[4];
    {
        float4v z = {0.f, 0.f, 0.f, 0.f};
        hacc[0] = z; hacc[1] = z; hacc[2] = z; hacc[3] = z;
        #pragma unroll 2
        for (int ks = 0; ks < 8; ks++) {
            int kbase = ks * 32 + kq;
            half8 Af[4];
            #pragma unroll
            for (int mt = 0; mt < 4; mt++)
                Af[mt] = *(const half8*)(&sA[1][(mt * 16 + l16) * SA + kbase]);
            half8 b0 = use_prep ? ldB(prep + FOBS_OFF, 16, nt, ks, lane)
                                : ldBraw(fobsW, 1.f, nullptr, 0.f, 0, HID, nt, ks, lane);
            #pragma unroll
            for (int mt = 0; mt < 4; mt++)
                hacc[mt] = __builtin_amdgcn_mfma_f32_16x16x32_f16(Af[mt], b0, hacc[mt], 0, 0, 0);
        }
        float bb = fobs_b[col];
        #pragma unroll
        for (int mt = 0; mt < 4; mt++)
            #pragma unroll
            for (int r = 0; r < 4; r++) {
                int row = mt * 16 + quad * 4 + r;
                float h = hacc[mt][r] + bb;
                hacc[mt][r] = h;                       // keep f32 h as GRU1 hold
                sA[0][row * SA + col] = (_Float16)h;
            }
    }
    __syncthreads();

    // ---- GRU1 fused (x=0 so gi = b_ih). A = T0 (h). Two row-half passes (= batches).
    #pragma unroll 1
    for (int half = 0; half < 2; half++) {
        const int rb = half * 32;
        float4v aR[2], aZ[2], aN[2];
        float4v z = {0.f, 0.f, 0.f, 0.f};
        aR[0] = z; aR[1] = z; aZ[0] = z; aZ[1] = z; aN[0] = z; aN[1] = z;
        #pragma unroll 2
        for (int ks = 0; ks < 8; ks++) {
            const int kbase = ks * 32 + kq;
            half8 A0 = *(const half8*)(&sA[0][(rb + l16) * SA + kbase]);
            half8 A1 = *(const half8*)(&sA[0][(rb + 16 + l16) * SA + kbase]);
            half8 bR = use_prep ? ldB(prep + WHH_OFF, 48,  0 + nt, ks, lane)
                                : ldBraw(whh, 1.f, nullptr, 0.f, 0, HID,  0 + nt, ks, lane);
            half8 bZ = use_prep ? ldB(prep + WHH_OFF, 48, 16 + nt, ks, lane)
                                : ldBraw(whh, 1.f, nullptr, 0.f, 0, HID, 16 + nt, ks, lane);
            half8 bN = use_prep ? ldB(prep + WHH_OFF, 48, 32 + nt, ks, lane)
                                : ldBraw(whh, 1.f, nullptr, 0.f, 0, HID, 32 + nt, ks, lane);
            aR[0] = __builtin_amdgcn_mfma_f32_16x16x32_f16(A0, bR, aR[0], 0, 0, 0);
            aR[1] = __builtin_amdgcn_mfma_f32_16x16x32_f16(A1, bR, aR[1], 0, 0, 0);
            aZ[0] = __builtin_amdgcn_mfma_f32_16x16x32_f16(A0, bZ, aZ[0], 0, 0, 0);
            aZ[1] = __builtin_amdgcn_mfma_f32_16x16x32_f16(A1, bZ, aZ[1], 0, 0, 0);
            aN[0] = __builtin_amdgcn_mfma_f32_16x16x32_f16(A0, bN, aN[0], 0, 0, 0);
            aN[1] = __builtin_amdgcn_mfma_f32_16x16x32_f16(A1, bN, aN[1], 0, 0, 0);
        }
        float biR = b_ih[col],       bhR = b_hh[col];
        float biZ = b_ih[256 + col], bhZ = b_hh[256 + col];
        float biN = b_ih[512 + col], bhN = b_hh[512 + col];
        float psum = 0.f;
        #pragma unroll
        for (int mt = 0; mt < 2; mt++)
            #pragma unroll
            for (int r = 0; r < 4; r++) {
                int row = rb + mt * 16 + quad * 4 + r;
                float rg = sigmoid_f(biR + aR[mt][r] + bhR);
                float zg = sigmoid_f(biZ + aZ[mt][r] + bhZ);
                float ng = tanh_f(biN + rg * (aN[mt][r] + bhN));
                float hold = hacc[half * 2 + mt][r];   // f32 h from regs, no LDS read
                float h1 = (1.f - zg) * ng + zg * hold;
                sA[1][row * SA + col] = (_Float16)h1;  // h1 -> T1
                psum += h1;
            }
        // column sum over this half's 32 rows (all in batch `half`)
        psum += __shfl_xor(psum, 16);
        psum += __shfl_xor(psum, 32);
        if (lane < 16) Scol[half][nt * 16 + lane] = psum;
    }
    __syncthreads();

    // ---- ep phase: ep[bat][j] = gS_j/32 + b_ih[j] (+ b_hh[j] for r,z), j in 0..767.
    // gS/32 = S @ (wih/32)^T via MFMA with virtual A (rows 0,1 = f16 colsums, rest 0).
    // wih/32 frags: j<512 -> WHH - COMB; j>=512 -> -WIHN.
    {
        float4v g[3];
        float4v zz = {0.f, 0.f, 0.f, 0.f};
        g[0] = zz; g[1] = zz; g[2] = zz;
        #pragma unroll 1
        for (int ks = 0; ks < 8; ks++) {
            const int kbase = ks * 32 + kq;
            half8 aS;
            #pragma unroll
            for (int j = 0; j < 8; j++) aS[j] = (_Float16)0.f;
            if (l16 < 2) {
                const float* Sp = &Scol[l16][kbase];
                float4v s0 = *(const float4v*)(Sp);
                float4v s1 = *(const float4v*)(Sp + 4);
                aS[0] = (_Float16)s0[0]; aS[1] = (_Float16)s0[1];
                aS[2] = (_Float16)s0[2]; aS[3] = (_Float16)s0[3];
                aS[4] = (_Float16)s1[0]; aS[5] = (_Float16)s1[1];
                aS[6] = (_Float16)s1[2]; aS[7] = (_Float16)s1[3];
            }
            #pragma unroll
            for (int i = 0; i < 3; i++) {
                int t3 = 3 * nt + i;           // 0..47, wave-uniform
                half8 bw;
                if (use_prep) {
                    if (t3 < 32) {
                        half8 x = ldB(prep + WHH_OFF,  48, t3, ks, lane);
                        half8 y = ldB(prep + COMB_OFF, 32, t3, ks, lane);
                        bw = x - y;            // = wih[t3-rows]/32
                    } else {
                        half8 x = ldB(prep + WIHN_OFF, 16, t3 - 32, ks, lane);
                        bw = half8{} - x;      // = wih(n)/32
                    }
                } else {
                    bw = ldBraw(wih, 0.03125f, nullptr, 0.f, 0, HID, t3, ks, lane);
                }
                g[i] = __builtin_amdgcn_mfma_f32_16x16x32_f16(aS, bw, g[i], 0, 0, 0);
            }
        }
        if (quad == 0) {
            #pragma unroll
            for (int i = 0; i < 3; i++) {
                int j = (3 * nt + i) * 16 + l16;
                float bi = b_ih[j];
                float bh = (j < 512) ? b_hh[j] : 0.f;   // uniform per i (tiles 16-aligned)
                ep[0][j] = g[i][0] + bi + bh;           // C row 0 = batch 0
                ep[1][j] = g[i][1] + bi + bh;           // C row 1 = batch 1
            }
        }
        if (tid < MROWS) Srow[tid] = 0.f;
    }
    __syncthreads();

    // ---- GRU2 fused on A = h1 only: aR/aZ via COMB (gh - G/32 in one acc),
    // aNi via WIHN (-G_n/32), aNh via WHH(n). Two row-half passes.
    #pragma unroll 1
    for (int half = 0; half < 2; half++) {
        const int rb = half * 32;
        float4v aR[2], aZ[2], aNi[2], aNh[2];
        float4v z = {0.f, 0.f, 0.f, 0.f};
        aR[0] = z; aR[1] = z; aZ[0] = z; aZ[1] = z;
        aNi[0] = z; aNi[1] = z; aNh[0] = z; aNh[1] = z;
        #pragma unroll 2
        for (int ks = 0; ks < 8; ks++) {
            const int kbase = ks * 32 + kq;
            half8 H0 = *(const half8*)(&sA[1][(rb + l16) * SA + kbase]);
            half8 H1 = *(const half8*)(&sA[1][(rb + 16 + l16) * SA + kbase]);
            half8 bR  = use_prep ? ldB(prep + COMB_OFF, 32,  0 + nt, ks, lane)
                                 : ldBraw(whh, 1.f, wih, -0.03125f, 0, HID,  0 + nt, ks, lane);
            half8 bZ  = use_prep ? ldB(prep + COMB_OFF, 32, 16 + nt, ks, lane)
                                 : ldBraw(whh, 1.f, wih, -0.03125f, 0, HID, 16 + nt, ks, lane);
            half8 bNi = use_prep ? ldB(prep + WIHN_OFF, 16, nt, ks, lane)
                                 : ldBraw(wih, -0.03125f, nullptr, 0.f, 512, HID, nt, ks, lane);
            half8 bNh = use_prep ? ldB(prep + WHH_OFF, 48, 32 + nt, ks, lane)
                                 : ldBraw(whh, 1.f, nullptr, 0.f, 0, HID, 32 + nt, ks, lane);
            aR[0]  = __builtin_amdgcn_mfma_f32_16x16x32_f16(H0, bR,  aR[0],  0, 0, 0);
            aR[1]  = __builtin_amdgcn_mfma_f32_16x16x32_f16(H1, bR,  aR[1],  0, 0, 0);
            aZ[0]  = __builtin_amdgcn_mfma_f32_16x16x32_f16(H0, bZ,  aZ[0],  0, 0, 0);
            aZ[1]  = __builtin_amdgcn_mfma_f32_16x16x32_f16(H1, bZ,  aZ[1],  0, 0, 0);
            aNi[0] = __builtin_amdgcn_mfma_f32_16x16x32_f16(H0, bNi, aNi[0], 0, 0, 0);
            aNi[1] = __builtin_amdgcn_mfma_f32_16x16x32_f16(H1, bNi, aNi[1], 0, 0, 0);
            aNh[0] = __builtin_amdgcn_mfma_f32_16x16x32_f16(H0, bNh, aNh[0], 0, 0, 0);
            aNh[1] = __builtin_amdgcn_mfma_f32_16x16x32_f16(H1, bNh, aNh[1], 0, 0, 0);
        }

        // epilogue + decoder fold for this half (bat = half)
        float epR = ep[half][col];
        float epZ = ep[half][256 + col];
        float epN = ep[half][512 + col];
        float bhN = b_hh[512 + col];
        float dw  = dec_W[col];
        float p[2][4];
        #pragma unroll
        for (int mt = 0; mt < 2; mt++)
            #pragma unroll
            for (int r = 0; r < 4; r++) {
                int row = rb + mt * 16 + quad * 4 + r;
                float rg = sigmoid_f(aR[mt][r] + epR);
                float zg = sigmoid_f(aZ[mt][r] + epZ);
                float ng = tanh_f(aNi[mt][r] + epN + rg * (aNh[mt][r] + bhN));
                float h1v = (float)sA[1][row * SA + col];
                float h2 = (1.f - zg) * ng + zg * h1v;
                p[mt][r] = h2 * dw;
            }
        #pragma unroll
        for (int m = 1; m <= 8; m <<= 1) {
            #pragma unroll
            for (int mt = 0; mt < 2; mt++)
                #pragma unroll
                for (int r = 0; r < 4; r++)
                    p[mt][r] += __shfl_xor(p[mt][r], m);
        }
        if (l16 == 0) {
            #pragma unroll
            for (int mt = 0; mt < 2; mt++)
                #pragma unroll
                for (int r = 0; r < 4; r++)
                    atomicAdd(&Srow[rb + mt * 16 + quad * 4 + r], p[mt][r]);
        }
    }
    __syncthreads();
    if (tid < MROWS) out[(size_t)b * MROWS + tid] = Srow[tid] + dec_b[0];
}

extern "C" void kernel_launch(void* const* d_in, const int* in_sizes, int n_in,
                              void* d_out, int out_size, void* d_ws, size_t ws_size,
                              hipStream_t stream) {
    const float* obs   = (const float*)d_in[0];
    // d_in[1] (act) is unused by the reference
    const float* encW  = (const float*)d_in[2];
    const float* encb  = (const float*)d_in[3];
    const float* fobsW = (const float*)d_in[4];
    const float* fobsb = (const float*)d_in[5];
    const float* wih   = (const float*)d_in[6];
    const float* bih   = (const float*)d_in[7];
    const float* whh   = (const float*)d_in[8];
    const float* bhh   = (const float*)d_in[9];
    const float* decW  = (const float*)d_in[10];
    const float* decb  = (const float*)d_in[11];
    float* out = (float*)d_out;

    _Float16* prep = (_Float16*)d_ws;
    int use_prep = (ws_size >= (size_t)PREP_TOTAL * sizeof(_Float16)) ? 1 : 0;
    if (use_prep) {
        prep_weights<<<(PREP_TOTAL + 255) / 256, 256, 0, stream>>>(encW, fobsW, wih, whh, prep);
    }
    commnet_fused<<<NB / 2, 1024, 0, stream>>>(obs, prep, encb, fobsb, bih, bhh, decW, decb, out,
                                               encW, fobsW, wih, whh, use_prep);
}

// Round 10
// 233.055 us; speedup vs baseline: 1.0977x; 1.0977x over previous
//
#include <hip/hip_runtime.h>
#include <hip/hip_fp16.h>

// CommNet critic forward, fully fused: 1 workgroup = 2 batches (64 agent-rows).
// All GEMMs via v_mfma_f32_16x16x32_f16 (fp32 accumulate). B=2048,A=32,D=128,H=256.
// V11 = V9 base (best: 172us) + comm phase DELETED:
//   GRU1's column-sum S is in-register per wave (each wave owns all 64 rows of its
//   16 cols), so c = (S - h1)/32 is computed in the GRU1 epilogue from f32 h1 regs
//   and written to a THIRD LDS buffer sA[2] (no race with waves still reading h from
//   sA[0]). Removes one barrier + one phase + Scol round-trip.
// Empirical laws from V2-V10: exactly 1 workgroup resident/CU (occupancy == one
// block's waves, regardless of LDS 35-86KB or 512/1024 thr) -> phases/barriers are
// the cost driver, not ALU counts (V10: -20% MFMA, +1 phase => +17% time).
// 1024-thr blocks always get a 64-VGPR budget -> keep per-pass live sets small.

#define NB   2048
#define NA   32
#define DIN  128
#define HID  256
#define SA   264   // f16 row stride for activation LDS tiles (528B stride -> 4-bank stagger)
#define MROWS 64   // 2 batches x 32 agents

typedef _Float16 half8  __attribute__((ext_vector_type(8)));
typedef float    float4v __attribute__((ext_vector_type(4)));

// f16 weight-fragment arena layout in d_ws (element offsets)
#define ENC_OFF    0
#define FOBS_OFF   32768
#define WIH_OFF    98304
#define WHH_OFF    294912
#define PREP_TOTAL 491520   // f16 elements -> 983040 bytes needed in ws

// Pre-arrange weights into exact MFMA B-fragment order, f16:
// frag[((ks*NT + nt)*64 + lane)*8 + j] = W[nt*16 + lane%16][ks*32 + (lane/16)*8 + j]
__global__ void prep_weights(const float* __restrict__ encW, const float* __restrict__ fobsW,
                             const float* __restrict__ wih,  const float* __restrict__ whh,
                             _Float16* __restrict__ prep) {
    int F = blockIdx.x * 256 + threadIdx.x;
    if (F >= PREP_TOTAL) return;
    const float* src; int K, NT, local = F;
    if (F < FOBS_OFF)     { src = encW;  K = 128; NT = 16; }
    else if (F < WIH_OFF) { src = fobsW; K = 256; NT = 16; local = F - FOBS_OFF; }
    else if (F < WHH_OFF) { src = wih;   K = 256; NT = 48; local = F - WIH_OFF; }
    else                  { src = whh;   K = 256; NT = 48; local = F - WHH_OFF; }
    int j    = local & 7;
    int lane = (local >> 3) & 63;
    int t    = local >> 9;
    int nt   = t % NT;
    int ks   = t / NT;
    int col  = nt * 16 + (lane & 15);
    int k    = ks * 32 + ((lane >> 4) << 3) + j;
    prep[F] = (_Float16)src[col * K + k];
}

// NaN-safe, clamp-free: exp saturates cleanly through the rcp.
__device__ __forceinline__ float sigmoid_f(float x) {
    return 1.f / (1.f + __expf(-x));
}
__device__ __forceinline__ float tanh_f(float x) {
    return 1.f - 2.f / (__expf(2.f * x) + 1.f);
}

// Load one MFMA B-fragment (16 cols x 32 k) either from prepped arena or raw fp32.
__device__ __forceinline__ half8 ldB(const _Float16* __restrict__ prepm, int NT, int nt, int ks,
                                     const float* __restrict__ raw, int K, int use_prep, int lane) {
    if (use_prep)
        return *(const half8*)(prepm + (((ks * NT + nt) * 64 + lane) << 3));
    half8 b;
    int l16 = lane & 15, kq = (lane >> 4) << 3;
    #pragma unroll
    for (int j = 0; j < 8; j++)
        b[j] = (_Float16)raw[(nt * 16 + l16) * K + ks * 32 + kq + j];
    return b;
}

__global__ __launch_bounds__(1024) void commnet_fused(
    const float* __restrict__ obs, const _Float16* __restrict__ prep,
    const float* __restrict__ enc_b, const float* __restrict__ fobs_b,
    const float* __restrict__ b_ih, const float* __restrict__ b_hh,
    const float* __restrict__ dec_W, const float* __restrict__ dec_b,
    float* __restrict__ out,
    const float* __restrict__ encW, const float* __restrict__ fobsW,
    const float* __restrict__ wih, const float* __restrict__ whh,
    int use_prep)
{
    const int b    = blockIdx.x;       // block handles batches 2b, 2b+1 (rows 0..63)
    const int tid  = threadIdx.x;
    const int lane = tid & 63;
    const int nt   = tid >> 6;         // wave 0..15 -> col tile nt (cols 16nt..16nt+15)
    const int l16  = lane & 15;
    const int quad = lane >> 4;
    const int kq   = quad << 3;
    const int col  = nt * 16 + l16;    // this lane's output column (fixed all phases)

    // sA[0]: obs -> h ; sA[1]: e -> h1 ; sA[2]: c
    __shared__ __align__(16) _Float16 sA[3][MROWS * SA];
    __shared__ float Srow[MROWS];      // decoder row accumulators

    // ---- stage obs (fp32 global -> f16 LDS): 64 rows x 128, one half8 per thread
    {
        const float* obsb = obs + (size_t)b * MROWS * DIN;
        int r   = tid >> 4;            // 16 chunks per 128-wide row, 64 rows
        int off = (tid & 15) << 3;
        const float* src = obsb + r * DIN + off;
        float4v v0 = *(const float4v*)(src);
        float4v v1 = *(const float4v*)(src + 4);
        half8 hv;
        hv[0] = (_Float16)v0[0]; hv[1] = (_Float16)v0[1];
        hv[2] = (_Float16)v0[2]; hv[3] = (_Float16)v0[3];
        hv[4] = (_Float16)v1[0]; hv[5] = (_Float16)v1[1];
        hv[6] = (_Float16)v1[2]; hv[7] = (_Float16)v1[3];
        *(half8*)(&sA[0][r * SA + off]) = hv;
        if (tid < MROWS) Srow[tid] = 0.f;
    }
    __syncthreads();

    // ---- encoder: e = relu(obs @ encW^T + enc_b) : T0 -> T1
    {
        float4v acc[4];
        float4v z = {0.f, 0.f, 0.f, 0.f};
        acc[0] = z; acc[1] = z; acc[2] = z; acc[3] = z;
        #pragma unroll
        for (int ks = 0; ks < 4; ks++) {
            int kbase = ks * 32 + kq;
            half8 Af[4];
            #pragma unroll
            for (int mt = 0; mt < 4; mt++)
                Af[mt] = *(const half8*)(&sA[0][(mt * 16 + l16) * SA + kbase]);
            half8 b0 = ldB(prep + ENC_OFF, 16, nt, ks, encW, DIN, use_prep, lane);
            #pragma unroll
            for (int mt = 0; mt < 4; mt++)
                acc[mt] = __builtin_amdgcn_mfma_f32_16x16x32_f16(Af[mt], b0, acc[mt], 0, 0, 0);
        }
        float bb = enc_b[col];
        #pragma unroll
        for (int mt = 0; mt < 4; mt++)
            #pragma unroll
            for (int r = 0; r < 4; r++) {
                int row = mt * 16 + quad * 4 + r;
                sA[1][row * SA + col] = (_Float16)fmaxf(acc[mt][r] + bb, 0.f);
            }
    }
    __syncthreads();

    // ---- fobs: h = e @ fobsW^T + fobs_b : T1 -> T0. Keep h (f32) in regs as GRU1's hold.
    float4v hacc[4];
    {
        float4v z = {0.f, 0.f, 0.f, 0.f};
        hacc[0] = z; hacc[1] = z; hacc[2] = z; hacc[3] = z;
        #pragma unroll 2
        for (int ks = 0; ks < 8; ks++) {
            int kbase = ks * 32 + kq;
            half8 Af[4];
            #pragma unroll
            for (int mt = 0; mt < 4; mt++)
                Af[mt] = *(const half8*)(&sA[1][(mt * 16 + l16) * SA + kbase]);
            half8 b0 = ldB(prep + FOBS_OFF, 16, nt, ks, fobsW, HID, use_prep, lane);
            #pragma unroll
            for (int mt = 0; mt < 4; mt++)
                hacc[mt] = __builtin_amdgcn_mfma_f32_16x16x32_f16(Af[mt], b0, hacc[mt], 0, 0, 0);
        }
        float bb = fobs_b[col];
        #pragma unroll
        for (int mt = 0; mt < 4; mt++)
            #pragma unroll
            for (int r = 0; r < 4; r++) {
                int row = mt * 16 + quad * 4 + r;
                float h = hacc[mt][r] + bb;
                hacc[mt][r] = h;                       // keep f32 h as GRU1 hold
                sA[0][row * SA + col] = (_Float16)h;
            }
    }
    __syncthreads();

    // ---- GRU1 fused (x=0 so gi = b_ih). A = T0 (h). Two row-half passes (= batches).
    // Epilogue also computes c = (S - h1)/32 from in-register S (full column owned by
    // this wave) and f32 h1, writing h1 -> sA[1] and c -> sA[2] (no comm phase).
    #pragma unroll 1
    for (int half = 0; half < 2; half++) {
        const int rb = half * 32;
        float4v aR[2], aZ[2], aN[2];
        float4v z = {0.f, 0.f, 0.f, 0.f};
        aR[0] = z; aR[1] = z; aZ[0] = z; aZ[1] = z; aN[0] = z; aN[1] = z;
        #pragma unroll 2
        for (int ks = 0; ks < 8; ks++) {
            const int kbase = ks * 32 + kq;
            half8 A0 = *(const half8*)(&sA[0][(rb + l16) * SA + kbase]);
            half8 A1 = *(const half8*)(&sA[0][(rb + 16 + l16) * SA + kbase]);
            half8 bR = ldB(prep + WHH_OFF, 48,  0 + nt, ks, whh, HID, use_prep, lane);
            half8 bZ = ldB(prep + WHH_OFF, 48, 16 + nt, ks, whh, HID, use_prep, lane);
            half8 bN = ldB(prep + WHH_OFF, 48, 32 + nt, ks, whh, HID, use_prep, lane);
            aR[0] = __builtin_amdgcn_mfma_f32_16x16x32_f16(A0, bR, aR[0], 0, 0, 0);
            aR[1] = __builtin_amdgcn_mfma_f32_16x16x32_f16(A1, bR, aR[1], 0, 0, 0);
            aZ[0] = __builtin_amdgcn_mfma_f32_16x16x32_f16(A0, bZ, aZ[0], 0, 0, 0);
            aZ[1] = __builtin_amdgcn_mfma_f32_16x16x32_f16(A1, bZ, aZ[1], 0, 0, 0);
            aN[0] = __builtin_amdgcn_mfma_f32_16x16x32_f16(A0, bN, aN[0], 0, 0, 0);
            aN[1] = __builtin_amdgcn_mfma_f32_16x16x32_f16(A1, bN, aN[1], 0, 0, 0);
        }
        float biR = b_ih[col],       bhR = b_hh[col];
        float biZ = b_ih[256 + col], bhZ = b_hh[256 + col];
        float biN = b_ih[512 + col], bhN = b_hh[512 + col];
        float h1v[2][4];
        float psum = 0.f;
        #pragma unroll
        for (int mt = 0; mt < 2; mt++)
            #pragma unroll
            for (int r = 0; r < 4; r++) {
                int row = rb + mt * 16 + quad * 4 + r;
                float rg = sigmoid_f(biR + aR[mt][r] + bhR);
                float zg = sigmoid_f(biZ + aZ[mt][r] + bhZ);
                float ng = tanh_f(biN + rg * (aN[mt][r] + bhN));
                float hold = hacc[half * 2 + mt][r];   // f32 h from regs, no LDS read
                float h1 = (1.f - zg) * ng + zg * hold;
                h1v[mt][r] = h1;
                sA[1][row * SA + col] = (_Float16)h1;  // h1 -> T1
                psum += h1;
            }
        // column sum over this half's 32 rows (this wave owns the whole column)
        psum += __shfl_xor(psum, 16);
        psum += __shfl_xor(psum, 32);
        // c = (S - h1)/32 -> T2, straight from registers
        #pragma unroll
        for (int mt = 0; mt < 2; mt++)
            #pragma unroll
            for (int r = 0; r < 4; r++) {
                int row = rb + mt * 16 + quad * 4 + r;
                sA[2][row * SA + col] = (_Float16)((psum - h1v[mt][r]) * (1.f / 32.f));
            }
    }
    __syncthreads();

    // ---- GRU2 fused: gi from c (T2) @ W_ih, gh from h1 (T1) @ W_hh.
    // Two row-half passes; r,z share accumulators; 32 acc regs per pass.
    #pragma unroll 1
    for (int half = 0; half < 2; half++) {
        const int rb = half * 32;
        float4v aR[2], aZ[2], aNi[2], aNh[2];
        float4v z = {0.f, 0.f, 0.f, 0.f};
        aR[0] = z; aR[1] = z; aZ[0] = z; aZ[1] = z;
        aNi[0] = z; aNi[1] = z; aNh[0] = z; aNh[1] = z;
        #pragma unroll 1
        for (int ks = 0; ks < 8; ks++) {
            const int kbase = ks * 32 + kq;
            // gi side: A = c
            {
                half8 C0 = *(const half8*)(&sA[2][(rb + l16) * SA + kbase]);
                half8 C1 = *(const half8*)(&sA[2][(rb + 16 + l16) * SA + kbase]);
                half8 bR = ldB(prep + WIH_OFF, 48,  0 + nt, ks, wih, HID, use_prep, lane);
                half8 bZ = ldB(prep + WIH_OFF, 48, 16 + nt, ks, wih, HID, use_prep, lane);
                half8 bN = ldB(prep + WIH_OFF, 48, 32 + nt, ks, wih, HID, use_prep, lane);
                aR[0]  = __builtin_amdgcn_mfma_f32_16x16x32_f16(C0, bR, aR[0], 0, 0, 0);
                aR[1]  = __builtin_amdgcn_mfma_f32_16x16x32_f16(C1, bR, aR[1], 0, 0, 0);
                aZ[0]  = __builtin_amdgcn_mfma_f32_16x16x32_f16(C0, bZ, aZ[0], 0, 0, 0);
                aZ[1]  = __builtin_amdgcn_mfma_f32_16x16x32_f16(C1, bZ, aZ[1], 0, 0, 0);
                aNi[0] = __builtin_amdgcn_mfma_f32_16x16x32_f16(C0, bN, aNi[0], 0, 0, 0);
                aNi[1] = __builtin_amdgcn_mfma_f32_16x16x32_f16(C1, bN, aNi[1], 0, 0, 0);
            }
            // gh side: A = h1
            {
                half8 H0 = *(const half8*)(&sA[1][(rb + l16) * SA + kbase]);
                half8 H1 = *(const half8*)(&sA[1][(rb + 16 + l16) * SA + kbase]);
                half8 bR = ldB(prep + WHH_OFF, 48,  0 + nt, ks, whh, HID, use_prep, lane);
                half8 bZ = ldB(prep + WHH_OFF, 48, 16 + nt, ks, whh, HID, use_prep, lane);
                half8 bN = ldB(prep + WHH_OFF, 48, 32 + nt, ks, whh, HID, use_prep, lane);
                aR[0]  = __builtin_amdgcn_mfma_f32_16x16x32_f16(H0, bR, aR[0], 0, 0, 0);
                aR[1]  = __builtin_amdgcn_mfma_f32_16x16x32_f16(H1, bR, aR[1], 0, 0, 0);
                aZ[0]  = __builtin_amdgcn_mfma_f32_16x16x32_f16(H0, bZ, aZ[0], 0, 0, 0);
                aZ[1]  = __builtin_amdgcn_mfma_f32_16x16x32_f16(H1, bZ, aZ[1], 0, 0, 0);
                aNh[0] = __builtin_amdgcn_mfma_f32_16x16x32_f16(H0, bN, aNh[0], 0, 0, 0);
                aNh[1] = __builtin_amdgcn_mfma_f32_16x16x32_f16(H1, bN, aNh[1], 0, 0, 0);
            }
        }

        // epilogue + decoder fold for this half
        float biR = b_ih[col],       bhR = b_hh[col];
        float biZ = b_ih[256 + col], bhZ = b_hh[256 + col];
        float biN = b_ih[512 + col], bhN = b_hh[512 + col];
        float dw  = dec_W[col];
        float p[2][4];
        #pragma unroll
        for (int mt = 0; mt < 2; mt++)
            #pragma unroll
            for (int r = 0; r < 4; r++) {
                int row = rb + mt * 16 + quad * 4 + r;
                float rg = sigmoid_f(aR[mt][r] + biR + bhR);
                float zg = sigmoid_f(aZ[mt][r] + biZ + bhZ);
                float ng = tanh_f((aNi[mt][r] + biN) + rg * (aNh[mt][r] + bhN));
                float h1v = (float)sA[1][row * SA + col];
                float h2 = (1.f - zg) * ng + zg * h1v;
                p[mt][r] = h2 * dw;
            }
        #pragma unroll
        for (int m = 1; m <= 8; m <<= 1) {
            #pragma unroll
            for (int mt = 0; mt < 2; mt++)
                #pragma unroll
                for (int r = 0; r < 4; r++)
                    p[mt][r] += __shfl_xor(p[mt][r], m);
        }
        if (l16 == 0) {
            #pragma unroll
            for (int mt = 0; mt < 2; mt++)
                #pragma unroll
                for (int r = 0; r < 4; r++)
                    atomicAdd(&Srow[rb + mt * 16 + quad * 4 + r], p[mt][r]);
        }
    }
    __syncthreads();
    if (tid < MROWS) out[(size_t)b * MROWS + tid] = Srow[tid] + dec_b[0];
}

extern "C" void kernel_launch(void* const* d_in, const int* in_sizes, int n_in,
                              void* d_out, int out_size, void* d_ws, size_t ws_size,
                              hipStream_t stream) {
    const float* obs   = (const float*)d_in[0];
    // d_in[1] (act) is unused by the reference
    const float* encW  = (const float*)d_in[2];
    const float* encb  = (const float*)d_in[3];
    const float* fobsW = (const float*)d_in[4];
    const float* fobsb = (const float*)d_in[5];
    const float* wih   = (const float*)d_in[6];
    const float* bih   = (const float*)d_in[7];
    const float* whh   = (const float*)d_in[8];
    const float* bhh   = (const float*)d_in[9];
    const float* decW  = (const float*)d_in[10];
    const float* decb  = (const float*)d_in[11];
    float* out = (float*)d_out;

    _Float16* prep = (_Float16*)d_ws;
    int use_prep = (ws_size >= (size_t)PREP_TOTAL * sizeof(_Float16)) ? 1 : 0;
    if (use_prep) {
        prep_weights<<<(PREP_TOTAL + 255) / 256, 256, 0, stream>>>(encW, fobsW, wih, whh, prep);
    }
    commnet_fused<<<NB / 2, 1024, 0, stream>>>(obs, prep, encb, fobsb, bih, bhh, decW, decb, out,
                                               encW, fobsW, wih, whh, use_prep);
}